// Round 10
// baseline (42.667 us; speedup 1.0000x reference)
//
#include <hip/hip_runtime.h>

// out[8,8192] = x[8,8192] @ W^T, W = dequant4(qweight, scale, zero), GROUP=128.
// qweight: one byte value (0..255) per int32, [8192 n][4096 k-bytes], 2 nibbles
// per byte, low nibble = even k.
//
// R10: single GEMM kernel (plus harness memset).
//  - KS=16 -> 512 blocks x 8 waves = 4096 waves: per-wave compute (~2700 cy)
//    dominates per-wave tails (~1400 cy). (R9 lesson: KS=32's short slices
//    were tail-dominated.)
//  - Block builds its A-slice (16 KB, bf16 fragments, rows 8..15 zero) in LDS
//    directly from x -- prep kernel folded in, one less dispatch.
//  - B group-0 prefetch issued BEFORE the A-build so cold weight latency
//    hides under build VALU. In-loop: A = ds_read_b128, B = 8x dwordx4
//    (only vmcnt stream), 1-group-deep prefetch.
//  - C layout (HW-verified): col=lane&15, row=(lane>>4)*4+reg; rows 0..7 real.

typedef __attribute__((ext_vector_type(8))) short bf16x8;
typedef __attribute__((ext_vector_type(4))) float f32x4;

constexpr int Mdim  = 8;
constexpr int N     = 8192;
constexpr int K     = 8192;
constexpr int NG    = 64;           // groups per row
constexpr int KS    = 16;           // K splits
constexpr int KSL   = K / KS;       // 512 k per slice
constexpr int GPS   = KSL / 128;    // 4 groups per slice
constexpr int ROWI4 = K / 8;        // 1024 int4 per weight row
constexpr int SLKK  = KSL / 32;     // 16 A k-blocks per slice

__device__ __forceinline__ float nib_lo(int q) {
    return __int_as_float((q & 15) | 0x4B000000) - 8388608.0f;      // exact
}
__device__ __forceinline__ float nib_hi(int q) {
    return __int_as_float(((q >> 4) & 15) | 0x4B000000) - 8388608.0f;
}
__device__ __forceinline__ int pkbf(float lo, float hi) {           // 2xf32 -> 2xbf16 (RNE)
    int r;
    asm("v_cvt_pk_bf16_f32 %0, %1, %2" : "=v"(r) : "v"(lo), "v"(hi));
    return r;
}

__global__ __launch_bounds__(512, 4) void qmfma_kernel(
    const float* __restrict__ x,      // [8, 8192]
    const int*   __restrict__ qw,     // [8192, 4096]
    const float* __restrict__ scale,  // [8192, 64]
    const float* __restrict__ zero,   // [8192, 64]
    float*       __restrict__ out)    // [8, 8192] pre-zeroed
{
    __shared__ int4 As[SLKK * 64];                // 16KB: this slice's A frags

    const int tid  = threadIdx.x;
    const int lane = tid & 63;
    const int wave = tid >> 6;
    const int bid  = blockIdx.x;                  // 512 blocks
    const int ks   = bid >> 5;                    // 0..15
    const int nb   = bid & 31;                    // n-block (256 cols)
    const int c0   = nb * 256 + wave * 32;        // wave's first col
    const int nl0  = c0 + (lane & 15);            // tile0 row / C col
    const int nl1  = nl0 + 16;                    // tile1
    const int kb   = lane >> 4;                   // k-quad 0..3

    const int4* __restrict__ qrow0 = reinterpret_cast<const int4*>(qw) + (size_t)nl0 * ROWI4;
    const int4* __restrict__ qrow1 = reinterpret_cast<const int4*>(qw) + (size_t)nl1 * ROWI4;

    const int g0 = ks * GPS;                      // first group of slice
    const int kq = ks * (KSL / 8);                // int4 offset of slice in a row

    // ---- B group-0 prefetch FIRST (latency hides under the A build below)
    int4 qc0[4], qc1[4], qn0[4], qn1[4];
    #pragma unroll
    for (int t = 0; t < 4; ++t) {
        qc0[t] = qrow0[kq + t * 4 + kb];
        qc1[t] = qrow1[kq + t * 4 + kb];
    }
    float s0 = scale[nl0 * NG + g0], z0 = zero[nl0 * NG + g0];
    float s1 = scale[nl1 * NG + g0], z1 = zero[nl1 * NG + g0];

    // ---- build A-slice in LDS: 1024 fragments, 2 per thread (rows 8..15 zero)
    #pragma unroll
    for (int j = tid; j < SLKK * 64; j += 512) {
        const int ll  = j & 63;                   // fragment lane
        const int kk  = j >> 6;                   // k-block within slice
        const int row = ll & 15;
        const int k0  = ks * KSL + kk * 32 + (ll >> 4) * 8;
        float4 xa = {0.f, 0.f, 0.f, 0.f}, xb = {0.f, 0.f, 0.f, 0.f};
        if (row < Mdim) {
            const float4* xr = reinterpret_cast<const float4*>(x) + (size_t)row * (K / 4);
            xa = xr[k0 / 4];
            xb = xr[k0 / 4 + 1];
        }
        int4 r;
        r.x = pkbf(xa.x, xa.y);
        r.y = pkbf(xa.z, xa.w);
        r.z = pkbf(xb.x, xb.y);
        r.w = pkbf(xb.z, xb.w);
        As[j] = r;
    }
    __syncthreads();

    f32x4 acc0 = {0.f, 0.f, 0.f, 0.f};
    f32x4 acc1 = {0.f, 0.f, 0.f, 0.f};

    #pragma unroll 1
    for (int g = 0; g < GPS; ++g) {
        const float cs0 = s0, csz0 = z0 * s0;
        const float cs1 = s1, csz1 = z1 * s1;

        if (g + 1 < GPS) {
            const int kqn = kq + (g + 1) * 16;
            #pragma unroll
            for (int t = 0; t < 4; ++t) {
                qn0[t] = qrow0[kqn + t * 4 + kb];
                qn1[t] = qrow1[kqn + t * 4 + kb];
            }
            s0 = scale[nl0 * NG + g0 + g + 1]; z0 = zero[nl0 * NG + g0 + g + 1];
            s1 = scale[nl1 * NG + g0 + g + 1]; z1 = zero[nl1 * NG + g0 + g + 1];
        }

        #pragma unroll
        for (int t = 0; t < 4; ++t) {
            // A fragment from LDS (ds_read_b128, conflict-free)
            union { int4 u; bf16x8 v; } A;
            A.u = As[(g * 4 + t) * 64 + lane];

            union { int4 u; bf16x8 v; } B0, B1;
            const int4 qa = qc0[t];
            B0.u.x = pkbf(fmaf(nib_lo(qa.x), cs0, -csz0), fmaf(nib_hi(qa.x), cs0, -csz0));
            B0.u.y = pkbf(fmaf(nib_lo(qa.y), cs0, -csz0), fmaf(nib_hi(qa.y), cs0, -csz0));
            B0.u.z = pkbf(fmaf(nib_lo(qa.z), cs0, -csz0), fmaf(nib_hi(qa.z), cs0, -csz0));
            B0.u.w = pkbf(fmaf(nib_lo(qa.w), cs0, -csz0), fmaf(nib_hi(qa.w), cs0, -csz0));
            const int4 qb = qc1[t];
            B1.u.x = pkbf(fmaf(nib_lo(qb.x), cs1, -csz1), fmaf(nib_hi(qb.x), cs1, -csz1));
            B1.u.y = pkbf(fmaf(nib_lo(qb.y), cs1, -csz1), fmaf(nib_hi(qb.y), cs1, -csz1));
            B1.u.z = pkbf(fmaf(nib_lo(qb.z), cs1, -csz1), fmaf(nib_hi(qb.z), cs1, -csz1));
            B1.u.w = pkbf(fmaf(nib_lo(qb.w), cs1, -csz1), fmaf(nib_hi(qb.w), cs1, -csz1));

            acc0 = __builtin_amdgcn_mfma_f32_16x16x32_bf16(A.v, B0.v, acc0, 0, 0, 0);
            acc1 = __builtin_amdgcn_mfma_f32_16x16x32_bf16(A.v, B1.v, acc1, 0, 0, 0);
        }

        #pragma unroll
        for (int t = 0; t < 4; ++t) { qc0[t] = qn0[t]; qc1[t] = qn1[t]; }
    }

    // C: col = lane&15, row = kb*4 + i; rows 0..7 real -> kb < 2 stores.
    if (kb < 2) {
        #pragma unroll
        for (int i = 0; i < 4; ++i) {
            const int m = kb * 4 + i;
            atomicAdd(&out[(size_t)m * N + nl0], acc0[i]);
            atomicAdd(&out[(size_t)m * N + nl1], acc1[i]);
        }
    }
}

extern "C" void kernel_launch(void* const* d_in, const int* in_sizes, int n_in,
                              void* d_out, int out_size, void* d_ws, size_t ws_size,
                              hipStream_t stream) {
    const float* x     = (const float*)d_in[0];
    const int*   qw    = (const int*)d_in[1];
    const float* scale = (const float*)d_in[2];
    const float* zero  = (const float*)d_in[3];
    float*       out   = (float*)d_out;

    hipMemsetAsync(out, 0, (size_t)Mdim * N * sizeof(float), stream);
    qmfma_kernel<<<(N / 256) * KS, 512, 0, stream>>>(x, qw, scale, zero, out);
}